// Round 8
// baseline (1417.756 us; speedup 1.0000x reference)
//
#include <hip/hip_runtime.h>
#include <hip/hip_bf16.h>
#include <math.h>

// x: [D=32, N=9216] fp32. 3 iters: w(i,j)=exp(3*<x_i,x_j>),
// x[:,j] <- 0.5*sum_i w*x[:,i]/sum_i w + 0.5*x[:,j]
// Output: [x3][x1][x2][x3].
// v9: fused persistent kernel, barrier poll FIXED. v7 polled with ACQUIRE
//     (buffer_inv per poll -> cache annihilation); v8 polled RELAXED (served
//     from the spinner's non-coherent XCD L2 -> release seen only on random
//     eviction; ~160us barriers, one 41ms outlier). v9 polls the coherence
//     point directly via atomic RMW fetch_add(flag,0) — fresh data, no cache
//     invalidation — hybrid with relaxed loads (RMW every 8th poll) so the
//     flag line doesn't serialize under 864 pollers. NSPLIT back to 12
//     (864 blocks <= 1024 guaranteed-resident @ launch_bounds(256,4)):
//     v8's 576 blocks made each accum phase 1.5x longer. Math identical to
//     verified v4 (distance-2 gll pipeline, sigma-permuted transpose-free
//     QK->PV, prescaled xbT, den ones-MFMA).

#define D 32
#define NPIX 9216
#define NSPLIT 12            // i-split; grid = 72*12 = 864 blocks
#define JB 128               // j per block = 4 waves * 32 j
#define NJB (NPIX / JB)      // 72
#define IPB (NPIX / NSPLIT)  // 768 i per block
#define ICH 64               // i staged per chunk (2 halves of 32)
#define NCH (IPB / ICH)      // 12 chunks = 4 groups of 3
#define TS  40               // combine transpose tile stride (shorts)
#define NGRID (NJB * NSPLIT) // 864 (<= 4/CU * 256 CU guaranteed residency)
#define CBLK (NPIX / 32)     // 288 combine blocks

typedef __attribute__((ext_vector_type(8))) short short8;
typedef __attribute__((ext_vector_type(4))) short short4v;
typedef __attribute__((ext_vector_type(4))) float f32x4;

#if __has_builtin(__builtin_amdgcn_exp2f)
#define EXP2F __builtin_amdgcn_exp2f
#else
#define EXP2F exp2f
#endif

// sqrt(3 * log2(e)); xbT is stored pre-scaled so the QK MFMA directly yields
// S' = 3*log2(e)*<x_i,x_j> and w = exp2(S') needs no per-element multiply.
#define SQC3 2.08040504f

__device__ __forceinline__ unsigned pack2_bf16(float a, float b) {
    union { __hip_bfloat162 h2; unsigned u; } c;
    c.h2 = __float22bfloat162_rn(make_float2(a, b));
    return c.u;
}
__device__ __forceinline__ short pack1_bf16(float a) {
    union { __hip_bfloat16 h; unsigned short s; } c;
    c.h = __float2bfloat16(a);
    return (short)c.s;
}

// async global->LDS, 16B per lane; LDS dest = wave-uniform base + lane*16.
__device__ __forceinline__ void gll16(const short* g, short* l) {
    __builtin_amdgcn_global_load_lds(
        (const __attribute__((address_space(1))) void*)g,
        (__attribute__((address_space(3))) void*)l, 16, 0, 0);
}

// Software grid barrier. Counter at bar[idx*32], flag at bar[idx*32+16]
// (separate cache lines). Arrival: agent-scope ACQ_REL RMW. Release: RMW on
// flag (visible at coherence point). Spin: relaxed load (cheap, may be
// stale-L2) with an RMW fetch_add(flag,0) every 8th poll — RMWs execute at
// the coherence point, guaranteeing bounded detection WITHOUT invalidating
// the spinner's caches (v7 bug) and without relying on eviction (v8 bug).
__device__ __forceinline__ void sw_sync(int* bar, int idx) {
    __threadfence();   // release prior stores
    __syncthreads();
    if (threadIdx.x == 0) {
        int* cnt  = bar + idx * 32;
        int* flag = bar + idx * 32 + 16;
        int old = __hip_atomic_fetch_add(cnt, 1, __ATOMIC_ACQ_REL,
                                         __HIP_MEMORY_SCOPE_AGENT);
        if (old == NGRID - 1) {
            __hip_atomic_fetch_add(flag, 1, __ATOMIC_ACQ_REL,
                                   __HIP_MEMORY_SCOPE_AGENT);
        } else {
            int it = 1;
            for (;;) {
                __builtin_amdgcn_s_sleep(16);
                int v;
                if ((it++ & 7) == 0)
                    v = __hip_atomic_fetch_add(flag, 0, __ATOMIC_RELAXED,
                                               __HIP_MEMORY_SCOPE_AGENT);
                else
                    v = __hip_atomic_load(flag, __ATOMIC_RELAXED,
                                          __HIP_MEMORY_SCOPE_AGENT);
                if (v) break;
            }
        }
    }
    __syncthreads();
    __threadfence();   // acquire: one inv after the barrier, not per poll
}

// One 64-i chunk: 2 halves x 2 jt, 5 MFMA + 8 exp2 + 4 cvt_pk each.
__device__ __forceinline__ void chunk_compute(
    const short* bT, const short* bV, const short8* bfrag, const short8 ones,
    f32x4 acc[2][2], f32x4 accden[2], int quad, int m)
{
#pragma unroll
    for (int h = 0; h < 2; ++h) {
        const int rb = (h * 128 + quad * 32 + m) * 8;
        short8 aT0 = *(const short8*)&bT[rb];          // QK A rows m (scaled)
        short8 aT1 = *(const short8*)&bT[rb + 128];    // QK A rows 16+m
        short8 aV0 = *(const short8*)&bV[rb];          // PV A rows d=m
        short8 aV1 = *(const short8*)&bV[rb + 128];    // PV A rows d=16+m

#pragma unroll
        for (int jt = 0; jt < 2; ++jt) {
            f32x4 z = {0.f, 0.f, 0.f, 0.f};
            // s0 regs r: S'[i=quad*8+r][j=m]; s1: S'[i=quad*8+4+r][j=m]
            f32x4 s0 = __builtin_amdgcn_mfma_f32_16x16x32_bf16(aT0, bfrag[jt], z, 0, 0, 0);
            f32x4 s1 = __builtin_amdgcn_mfma_f32_16x16x32_bf16(aT1, bfrag[jt], z, 0, 0, 0);

            float w[8];
#pragma unroll
            for (int r = 0; r < 4; ++r) { w[r]     = EXP2F(s0[r]);
                                          w[4 + r] = EXP2F(s1[r]); }

            // In-register B-frag of w: element e = i-offset quad*8+e
            union { short8 s; unsigned u[4]; } wb;
            wb.u[0] = pack2_bf16(w[0], w[1]);
            wb.u[1] = pack2_bf16(w[2], w[3]);
            wb.u[2] = pack2_bf16(w[4], w[5]);
            wb.u[3] = pack2_bf16(w[6], w[7]);

            // den[j] += sum_i w[i][j]  (ones-row MFMA, matrix pipe)
            accden[jt] = __builtin_amdgcn_mfma_f32_16x16x32_bf16(ones, wb.s, accden[jt], 0, 0, 0);
            // num[d][j] += x[d][i] * w[i][j]  (M=d, N=j, K=i=32)
            acc[0][jt] = __builtin_amdgcn_mfma_f32_16x16x32_bf16(aV0, wb.s, acc[0][jt], 0, 0, 0);
            acc[1][jt] = __builtin_amdgcn_mfma_f32_16x16x32_bf16(aV1, wb.s, acc[1][jt], 0, 0, 0);
        }
    }
}

// num_part[bi][d][j] = sum_{i in split bi} w(i,j)*x[d][i]; den likewise.
__device__ __forceinline__ void accum_body(
    const short* __restrict__ xb, const short* __restrict__ xbT,
    float* __restrict__ num_part, float* __restrict__ den_part,
    short (*sT)[2048], short (*sV)[2048])
{
    const int t = threadIdx.x;
    const int wid = t >> 6, lane = t & 63, quad = lane >> 4, m = lane & 15;
    const int bj = blockIdx.x % NJB, bi = blockIdx.x / NJB;
    const int j0 = bj * JB + wid * 32;
    const int i0b = bi * IPB;

    // QK B-frags (j side, scaled): B[k=d][n=j_local]; lane: n=m, k=quad*8+e
    short8 bfrag[2];
#pragma unroll
    for (int jt = 0; jt < 2; ++jt)
        bfrag[jt] = *(const short8*)&xbT[(size_t)(j0 + jt * 16 + m) * D + quad * 8];

    short8 ones;
#pragma unroll
    for (int e = 0; e < 8; ++e) ones[e] = (short)0x3F80;   // bf16 1.0

    f32x4 acc[2][2] = {};       // [d-tile][j-tile], C-layout
    f32x4 accden[2] = {};       // den accumulator (rows redundant)

    // staging source addresses: cell c = t
    const int ch = t >> 7, cq = (t >> 5) & 3, ci = t & 31;
    // inverse of sigma(il) = ((il&4)<<2) + ((il>>3)<<2) + (il&3)
    const int invi = (((ci >> 3) & 1) << 4) | (((ci >> 2) & 1) << 3)
                   | (((ci >> 4) & 1) << 2) | (ci & 3);
    const short* srcT = xbT + (size_t)(i0b + ch * 32 + invi) * D + cq * 8;
    const short* srcV = xb + (size_t)ci * NPIX + i0b + ch * 32 + cq * 8;
    short* dT = &sT[0][0] + wid * 512;   // wave-uniform; +2048 per buffer
    short* dV = &sV[0][0] + wid * 512;

    // prologue: stage chunks 0 and 1
    gll16(srcT, dT);
    gll16(srcV, dV);
    gll16(srcT + (size_t)ICH * D, dT + 2048);
    gll16(srcV + ICH,             dV + 2048);
    const short* pT = srcT + 2 * (size_t)ICH * D;   // next prefetch src
    const short* pV = srcV + 2 * ICH;

    // chunk n (buffer k=n%3): wait for chunk issued 2 iters ago, barrier,
    // prefetch chunk n+2 into buffer (k+2)%3, compute buffer k.
#define CHUNK(n, k)                                                          \
    {                                                                        \
        if ((n) + 1 < NCH) asm volatile("s_waitcnt vmcnt(2)" ::: "memory");  \
        else               asm volatile("s_waitcnt vmcnt(0)" ::: "memory");  \
        __builtin_amdgcn_s_barrier();                                        \
        __builtin_amdgcn_sched_barrier(0);                                   \
        if ((n) + 2 < NCH) {                                                 \
            gll16(pT, dT + (((k) + 2) % 3) * 2048);                          \
            gll16(pV, dV + (((k) + 2) % 3) * 2048);                          \
            pT += (size_t)ICH * D; pV += ICH;                                \
        }                                                                    \
        chunk_compute(&sT[(k)][0], &sV[(k)][0], bfrag, ones, acc, accden,    \
                      quad, m);                                              \
    }

    for (int g = 0; g < NCH / 3; ++g) {   // 4 groups x 3 chunks (I$-small)
        const int n0 = 3 * g;
        CHUNK(n0 + 0, 0)
        CHUNK(n0 + 1, 1)
        CHUNK(n0 + 2, 2)
    }
#undef CHUNK

    // Plain coalesced stores of this split's partials.
    float* np = num_part + (size_t)bi * D * NPIX;
#pragma unroll
    for (int dt = 0; dt < 2; ++dt)
#pragma unroll
        for (int jt = 0; jt < 2; ++jt)
#pragma unroll
            for (int r = 0; r < 4; ++r)
                np[(dt * 16 + quad * 4 + r) * NPIX + j0 + jt * 16 + m] = acc[dt][jt][r];
#pragma unroll
    for (int jt = 0; jt < 2; ++jt)
        if (quad == 0) den_part[bi * NPIX + j0 + jt * 16 + m] = accden[jt][0];
}

// v = 0.5*(sum_s num)/(sum_s den) + 0.5*xin (or v=xin if !do_ms); writes
// xout/xfinal (fp32), xb (bf16 [D][N]), xbT (bf16 [N][D], scaled by SQC3).
__device__ __forceinline__ void combine_body(
    const float* __restrict__ xin,
    const float* __restrict__ num_part, const float* __restrict__ den_part,
    float* __restrict__ xout, float* __restrict__ xfinal,
    short* __restrict__ xb, short* __restrict__ xbT, int do_ms, short* tile)
{
    const int t = threadIdx.x;
    const int il = t & 31, q = t >> 5;
    const int i = blockIdx.x * 32 + il;
    const int d0 = q * 4;

    float inv = 0.f;
    if (do_ms) {
        float den = 0.f;
#pragma unroll
        for (int s = 0; s < NSPLIT; ++s) den += den_part[s * NPIX + i];
        inv = 0.5f / den;
    }

#pragma unroll
    for (int dd = 0; dd < 4; ++dd) {
        const int d = d0 + dd;
        const int idx = d * NPIX + i;
        float v;
        if (do_ms) {
            float nm = 0.f;
#pragma unroll
            for (int s = 0; s < NSPLIT; ++s) nm += num_part[(s * D + d) * NPIX + i];
            v = nm * inv + 0.5f * xin[idx];
            xout[idx] = v;
            if (xfinal) xfinal[idx] = v;
        } else {
            v = xin[idx];
        }
        xb[idx] = pack1_bf16(v);
        tile[il * TS + d] = pack1_bf16(v * SQC3);   // QK side pre-scaled
    }
    __syncthreads();
    const int i2 = t >> 3, dc = (t & 7) * 4;
    *(short4v*)&xbT[(blockIdx.x * 32 + i2) * D + dc] =
        *(const short4v*)&tile[i2 * TS + dc];
}

__global__ __launch_bounds__(256, 4) void fused_kernel(
    const float* __restrict__ x0, float* __restrict__ out,
    float* __restrict__ num_part, float* __restrict__ den_part,
    short* __restrict__ xb, short* __restrict__ xbT, int* __restrict__ bar)
{
    __shared__ __align__(16) short sT[3][2048];
    __shared__ __align__(16) short sV[3][2048];
    __shared__ __align__(16) short tile[32 * TS];
    const size_t slot = (size_t)D * NPIX;

    // A0: convert x0 -> xb/xbT
    if (blockIdx.x < CBLK)
        combine_body(x0, nullptr, nullptr, nullptr, nullptr, xb, xbT, 0, tile);
    sw_sync(bar, 0);

    for (int t = 0; t < 3; ++t) {
        accum_body(xb, xbT, num_part, den_part, sT, sV);
        sw_sync(bar, 1 + 2 * t);
        if (blockIdx.x < CBLK) {
            const float* xin = (t == 0) ? x0 : out + (size_t)t * slot;
            combine_body(xin, num_part, den_part, out + (size_t)(t + 1) * slot,
                         (t == 2) ? out : nullptr, xb, xbT, 1, tile);
        }
        if (t < 2) sw_sync(bar, 2 + 2 * t);
    }
}

extern "C" void kernel_launch(void* const* d_in, const int* in_sizes, int n_in,
                              void* d_out, int out_size, void* d_ws, size_t ws_size,
                              hipStream_t stream)
{
    const float* x0 = (const float*)d_in[0];
    float* out = (float*)d_out;              // [x3][x1][x2][x3]
    const size_t slot = (size_t)D * NPIX;

    float* num_part = (float*)d_ws;                        // NSPLIT*D*NPIX f32
    float* den_part = num_part + (size_t)NSPLIT * slot;    // NSPLIT*NPIX f32
    short* xb  = (short*)(den_part + (size_t)NSPLIT * NPIX);
    short* xbT = xb + slot;
    int*   bar = (int*)(xbT + slot);                       // 6 x {cnt,flag} lines

    hipMemsetAsync(bar, 0, 6 * 32 * sizeof(int), stream);  // replay-safe
    fused_kernel<<<dim3(NGRID), dim3(256), 0, stream>>>(
        x0, out, num_part, den_part, xb, xbT, bar);
}

// Round 10
// 148.082 us; speedup vs baseline: 9.5741x; 9.5741x over previous
//
#include <hip/hip_runtime.h>
#include <hip/hip_bf16.h>
#include <math.h>

// x: [D=32, N=9216] fp32. 3 iters: w(i,j)=exp(3*<x_i,x_j>),
// x[:,j] <- 0.5*sum_i w*x[:,i]/sum_i w + 0.5*x[:,j]
// Output: [x3][x1][x2][x3].
// v10 (resubmit; round-9 bench was an infra failure, kernel never ran):
//      REVERT to the verified v4 multi-launch structure (fused persistent
//      kernel abandoned: 3 barrier designs all failed on non-coherent XCD
//      L2s — acquire-poll wrecked caches, relaxed-poll relied on eviction,
//      RMW-poll still showed ms-scale outliers). One change vs v4: accum
//      uses 8-WAVE blocks (JB 256, grid 432) — halves the redundant T/V
//      staging traffic (each i-slice staged by 36 j-blocks instead of 72).
//      Waves 0-3 stage T, waves 4-7 stage V (1 gll16/chunk/wave, vmcnt(1)
//      distance-2 pipeline). Per-wave inner loop byte-identical to v4.

#define D 32
#define NPIX 9216
#define NSPLIT 12            // i-split; grid = 36*12 = 432 blocks (2/CU)
#define JB 256               // j per block = 8 waves * 32 j
#define NJB (NPIX / JB)      // 36
#define IPB (NPIX / NSPLIT)  // 768 i per block
#define ICH 64               // i staged per chunk (2 halves of 32)
#define NCH (IPB / ICH)      // 12 chunks = 4 groups of 3
#define TS  40               // combine transpose tile stride (shorts)

typedef __attribute__((ext_vector_type(8))) short short8;
typedef __attribute__((ext_vector_type(4))) short short4v;
typedef __attribute__((ext_vector_type(4))) float f32x4;

#if __has_builtin(__builtin_amdgcn_exp2f)
#define EXP2F __builtin_amdgcn_exp2f
#else
#define EXP2F exp2f
#endif

// sqrt(3 * log2(e)); xbT is stored pre-scaled so the QK MFMA directly yields
// S' = 3*log2(e)*<x_i,x_j> and w = exp2(S') needs no per-element multiply.
#define SQC3 2.08040504f

__device__ __forceinline__ unsigned pack2_bf16(float a, float b) {
    union { __hip_bfloat162 h2; unsigned u; } c;
    c.h2 = __float22bfloat162_rn(make_float2(a, b));
    return c.u;
}
__device__ __forceinline__ short pack1_bf16(float a) {
    union { __hip_bfloat16 h; unsigned short s; } c;
    c.h = __float2bfloat16(a);
    return (short)c.s;
}

// async global->LDS, 16B per lane; LDS dest = wave-uniform base + lane*16.
__device__ __forceinline__ void gll16(const short* g, short* l) {
    __builtin_amdgcn_global_load_lds(
        (const __attribute__((address_space(1))) void*)g,
        (__attribute__((address_space(3))) void*)l, 16, 0, 0);
}

// One 64-i chunk: 2 halves x 2 jt, 5 MFMA + 8 exp2 + 4 cvt_pk each.
__device__ __forceinline__ void chunk_compute(
    const short* bT, const short* bV, const short8* bfrag, const short8 ones,
    f32x4 acc[2][2], f32x4 accden[2], int quad, int m)
{
#pragma unroll
    for (int h = 0; h < 2; ++h) {
        const int rb = (h * 128 + quad * 32 + m) * 8;
        short8 aT0 = *(const short8*)&bT[rb];          // QK A rows m (scaled)
        short8 aT1 = *(const short8*)&bT[rb + 128];    // QK A rows 16+m
        short8 aV0 = *(const short8*)&bV[rb];          // PV A rows d=m
        short8 aV1 = *(const short8*)&bV[rb + 128];    // PV A rows d=16+m

#pragma unroll
        for (int jt = 0; jt < 2; ++jt) {
            f32x4 z = {0.f, 0.f, 0.f, 0.f};
            // s0 regs r: S'[i=quad*8+r][j=m]; s1: S'[i=quad*8+4+r][j=m]
            f32x4 s0 = __builtin_amdgcn_mfma_f32_16x16x32_bf16(aT0, bfrag[jt], z, 0, 0, 0);
            f32x4 s1 = __builtin_amdgcn_mfma_f32_16x16x32_bf16(aT1, bfrag[jt], z, 0, 0, 0);

            float w[8];
#pragma unroll
            for (int r = 0; r < 4; ++r) { w[r]     = EXP2F(s0[r]);
                                          w[4 + r] = EXP2F(s1[r]); }

            // In-register B-frag of w: element e = i-offset quad*8+e
            union { short8 s; unsigned u[4]; } wb;
            wb.u[0] = pack2_bf16(w[0], w[1]);
            wb.u[1] = pack2_bf16(w[2], w[3]);
            wb.u[2] = pack2_bf16(w[4], w[5]);
            wb.u[3] = pack2_bf16(w[6], w[7]);

            // den[j] += sum_i w[i][j]  (ones-row MFMA, matrix pipe)
            accden[jt] = __builtin_amdgcn_mfma_f32_16x16x32_bf16(ones, wb.s, accden[jt], 0, 0, 0);
            // num[d][j] += x[d][i] * w[i][j]  (M=d, N=j, K=i=32)
            acc[0][jt] = __builtin_amdgcn_mfma_f32_16x16x32_bf16(aV0, wb.s, acc[0][jt], 0, 0, 0);
            acc[1][jt] = __builtin_amdgcn_mfma_f32_16x16x32_bf16(aV1, wb.s, acc[1][jt], 0, 0, 0);
        }
    }
}

// num_part[bi][d][j] = sum_{i in split bi} w(i,j)*x[d][i]; den likewise.
// 8 waves: waves 0-3 stage T cells, waves 4-7 stage V cells (1 gll16 each
// per chunk); all waves compute (each owns 32 j via wid).
__global__ __launch_bounds__(512, 4) void accum_kernel(
    const short* __restrict__ xb,    // bf16 bits [D][NPIX]
    const short* __restrict__ xbT,   // bf16 bits [NPIX][D], pre-scaled by SQC3
    float* __restrict__ num_part,    // [NSPLIT][D][NPIX]
    float* __restrict__ den_part)    // [NSPLIT][NPIX]
{
    // LDS layout (both arrays): cell c = h*128 + q*32 + r, 8 shorts/cell.
    //   sT: row r of half h holds x'_{i0 + h*32 + inv_sigma(r)}, d-cols q*8..+7
    //   sV: row r = d, i-cols q*8..q*8+7 of half h
    // ds_read_b128 at (h*128 + quad*32 + m)*8: each 8-lane group covers all
    // 32 banks -> conflict-free. Triple-buffered, prefetch distance 2.
    __shared__ __align__(16) short sT[3][2048];
    __shared__ __align__(16) short sV[3][2048];

    const int t = threadIdx.x;
    const int wid = t >> 6, lane = t & 63, quad = lane >> 4, m = lane & 15;
    const int bj = blockIdx.x % NJB, bi = blockIdx.x / NJB;
    const int j0 = bj * JB + wid * 32;
    const int i0b = bi * IPB;

    // QK B-frags (j side, scaled): B[k=d][n=j_local]; lane: n=m, k=quad*8+e
    short8 bfrag[2];
#pragma unroll
    for (int jt = 0; jt < 2; ++jt)
        bfrag[jt] = *(const short8*)&xbT[(size_t)(j0 + jt * 16 + m) * D + quad * 8];

    short8 ones;
#pragma unroll
    for (int e = 0; e < 8; ++e) ones[e] = (short)0x3F80;   // bf16 1.0

    f32x4 acc[2][2] = {};       // [d-tile][j-tile], C-layout
    f32x4 accden[2] = {};       // den accumulator (rows redundant)

    // staging: cell c = t&255 (waves 0-3 -> T, waves 4-7 -> V)
    const bool isT = (t < 256);
    const int c = t & 255;
    const int ch = c >> 7, cq = (c >> 5) & 3, ci = c & 31;
    // inverse of sigma(il) = ((il&4)<<2) + ((il>>3)<<2) + (il&3)
    const int invi = (((ci >> 3) & 1) << 4) | (((ci >> 2) & 1) << 3)
                   | (((ci >> 4) & 1) << 2) | (ci & 3);
    const short* src0 = isT
        ? xbT + (size_t)(i0b + ch * 32 + invi) * D + cq * 8
        : xb + (size_t)ci * NPIX + i0b + ch * 32 + cq * 8;
    const size_t srcStep = isT ? (size_t)ICH * D : (size_t)ICH;  // per chunk
    short* dst = (isT ? &sT[0][0] : &sV[0][0]) + (wid & 3) * 512;  // wave-uniform

    // prologue: stage chunks 0 and 1 (1 load per wave per chunk)
    gll16(src0, dst);
    gll16(src0 + srcStep, dst + 2048);
    const short* psrc = src0 + 2 * srcStep;   // next prefetch src

    // chunk n (buffer k=n%3): wait for chunk issued 2 iters ago (vmcnt(1):
    // only chunk n+1's single load may remain outstanding), barrier,
    // prefetch chunk n+2 into buffer (k+2)%3, compute buffer k.
#define CHUNK(n, k)                                                          \
    {                                                                        \
        if ((n) + 1 < NCH) asm volatile("s_waitcnt vmcnt(1)" ::: "memory");  \
        else               asm volatile("s_waitcnt vmcnt(0)" ::: "memory");  \
        __builtin_amdgcn_s_barrier();                                        \
        __builtin_amdgcn_sched_barrier(0);                                   \
        if ((n) + 2 < NCH) {                                                 \
            gll16(psrc, dst + (((k) + 2) % 3) * 2048);                       \
            psrc += srcStep;                                                 \
        }                                                                    \
        chunk_compute(&sT[(k)][0], &sV[(k)][0], bfrag, ones, acc, accden,    \
                      quad, m);                                              \
    }

    for (int g = 0; g < NCH / 3; ++g) {   // 4 groups x 3 chunks (I$-small)
        CHUNK(3 * g + 0, 0)
        CHUNK(3 * g + 1, 1)
        CHUNK(3 * g + 2, 2)
    }
#undef CHUNK

    // Plain coalesced stores of this split's partials.
    float* np = num_part + (size_t)bi * D * NPIX;
#pragma unroll
    for (int dt = 0; dt < 2; ++dt)
#pragma unroll
        for (int jt = 0; jt < 2; ++jt)
#pragma unroll
            for (int r = 0; r < 4; ++r)
                np[(dt * 16 + quad * 4 + r) * NPIX + j0 + jt * 16 + m] = acc[dt][jt][r];
#pragma unroll
    for (int jt = 0; jt < 2; ++jt)
        if (quad == 0) den_part[bi * NPIX + j0 + jt * 16 + m] = accden[jt][0];
}

// v = 0.5*(sum_s num)/(sum_s den) + 0.5*xin (or v=xin if !do_ms); writes
// xout/xfinal (fp32), xb (bf16 [D][N]), xbT (bf16 [N][D], scaled by SQC3,
// via LDS transpose). 288 blocks x 32 i; thread t: i=(t&31), d=(t>>5)*4..+3.
__global__ __launch_bounds__(256) void combine_kernel(
    const float* __restrict__ xin,
    const float* __restrict__ num_part, const float* __restrict__ den_part,
    float* __restrict__ xout, float* __restrict__ xfinal,
    short* __restrict__ xb, short* __restrict__ xbT, int do_ms)
{
    __shared__ __align__(16) short tile[32 * TS];   // [i_local][d], scaled
    const int t = threadIdx.x;
    const int il = t & 31, q = t >> 5;
    const int i = blockIdx.x * 32 + il;
    const int d0 = q * 4;

    float inv = 0.f;
    if (do_ms) {
        float den = 0.f;
#pragma unroll
        for (int s = 0; s < NSPLIT; ++s) den += den_part[s * NPIX + i];
        inv = 0.5f / den;
    }

#pragma unroll
    for (int dd = 0; dd < 4; ++dd) {
        const int d = d0 + dd;
        const int idx = d * NPIX + i;
        float v;
        if (do_ms) {
            float nm = 0.f;
#pragma unroll
            for (int s = 0; s < NSPLIT; ++s) nm += num_part[(s * D + d) * NPIX + i];
            v = nm * inv + 0.5f * xin[idx];
            xout[idx] = v;
            if (xfinal) xfinal[idx] = v;
        } else {
            v = xin[idx];
        }
        xb[idx] = pack1_bf16(v);
        tile[il * TS + d] = pack1_bf16(v * SQC3);   // QK side pre-scaled
    }
    __syncthreads();
    // xbT rows: thread t writes 4 shorts (8 B) at xbT[i2][dc..dc+3]
    const int i2 = t >> 3, dc = (t & 7) * 4;
    *(short4v*)&xbT[(blockIdx.x * 32 + i2) * D + dc] =
        *(const short4v*)&tile[i2 * TS + dc];
}

extern "C" void kernel_launch(void* const* d_in, const int* in_sizes, int n_in,
                              void* d_out, int out_size, void* d_ws, size_t ws_size,
                              hipStream_t stream)
{
    const float* x0 = (const float*)d_in[0];
    float* out = (float*)d_out;              // [x3][x1][x2][x3]
    const size_t slot = (size_t)D * NPIX;

    float* num_part = (float*)d_ws;                        // NSPLIT*D*NPIX f32
    float* den_part = num_part + (size_t)NSPLIT * slot;    // NSPLIT*NPIX f32
    short* xb  = (short*)(den_part + (size_t)NSPLIT * NPIX);
    short* xbT = xb + slot;

    // convert x0 -> xb/xbT
    combine_kernel<<<dim3(NPIX / 32), dim3(256), 0, stream>>>(
        x0, nullptr, nullptr, nullptr, nullptr, xb, xbT, 0);

    for (int t = 0; t < 3; ++t) {
        accum_kernel<<<dim3(NJB * NSPLIT), dim3(512), 0, stream>>>(
            xb, xbT, num_part, den_part);
        const float* xin = (t == 0) ? x0 : (out + (size_t)t * slot);
        combine_kernel<<<dim3(NPIX / 32), dim3(256), 0, stream>>>(
            xin, num_part, den_part, out + (size_t)(t + 1) * slot,
            (t == 2) ? out : nullptr, xb, xbT, 1);
    }
}